// Round 1
// baseline (224.603 us; speedup 1.0000x reference)
//
#include <hip/hip_runtime.h>

#define BATCH 32
#define SEQ 512
#define CH 384
#define MAXL 4096
#define CH4 (CH / 4)   // 96 float4 per row

// Kernel 1: per-batch cumsum of durations, build t->frame-index table (-1 past total),
// write index table to workspace and mel_mask (as 0.0/1.0 floats) to d_out tail.
__global__ __launch_bounds__(SEQ) void lr_scan_kernel(
    const int* __restrict__ durations,
    const int* __restrict__ max_len_p,
    int* __restrict__ ws_idx,
    float* __restrict__ out_mask)
{
    __shared__ int s_cum[SEQ];
    __shared__ int s_idx[MAXL];

    const int tid = threadIdx.x;
    const int b = blockIdx.x;
    const int maxlen = max_len_p[0];

    // inclusive scan (Hillis-Steele) over 512 durations
    s_cum[tid] = durations[b * SEQ + tid];
    __syncthreads();
    #pragma unroll
    for (int off = 1; off < SEQ; off <<= 1) {
        int v = (tid >= off) ? s_cum[tid - off] : 0;
        __syncthreads();
        s_cum[tid] += v;
        __syncthreads();
    }

    // default: -1 means "t >= total" (masked, write zeros)
    for (int t = tid; t < MAXL; t += SEQ) s_idx[t] = -1;
    __syncthreads();

    // frame tid covers output positions [ends[tid-1], ends[tid]) after clipping.
    int e = min(s_cum[tid], maxlen);
    int st = (tid == 0) ? 0 : min(s_cum[tid - 1], maxlen);
    e = min(e, MAXL);
    st = min(st, MAXL);
    for (int t = st; t < e; ++t) s_idx[t] = tid;  // disjoint intervals, no races
    __syncthreads();

    for (int t = tid; t < MAXL; t += SEQ) {
        int v = s_idx[t];
        ws_idx[b * MAXL + t] = v;
        out_mask[b * MAXL + t] = (v < 0) ? 1.0f : 0.0f;
    }
}

// Kernel 2: expanded[b,t,:] = (idx>=0) ? x[b,idx,:] : 0, fully coalesced float4 writes.
// Each block handles 8 output rows (8 * 96 = 768 float4) with 256 threads (3 each).
__global__ __launch_bounds__(256) void lr_expand_kernel(
    const float4* __restrict__ x,
    const int* __restrict__ ws_idx,
    float4* __restrict__ out)
{
    const int r0 = blockIdx.x * 8;
    #pragma unroll
    for (int k = 0; k < 3; ++k) {
        int local = threadIdx.x + k * 256;      // 0..767
        int lr = local / CH4;                   // row within block (magic-mul)
        int c4 = local - lr * CH4;              // float4 column 0..95
        int r = r0 + lr;                        // global row = b*4096 + t
        int idx = ws_idx[r];                    // L1-hot, broadcast across 96 lanes
        float4 v = make_float4(0.f, 0.f, 0.f, 0.f);
        if (idx >= 0) {
            int b = r >> 12;                    // r / 4096
            v = x[(b * SEQ + idx) * CH4 + c4];
        }
        out[(size_t)r * CH4 + c4] = v;
    }
}

extern "C" void kernel_launch(void* const* d_in, const int* in_sizes, int n_in,
                              void* d_out, int out_size, void* d_ws, size_t ws_size,
                              hipStream_t stream) {
    const float* x = (const float*)d_in[0];
    const int* durations = (const int*)d_in[1];
    const int* max_len_p = (const int*)d_in[2];
    float* out = (float*)d_out;
    float* out_mask = out + (size_t)BATCH * MAXL * CH;  // mask follows expanded
    int* ws_idx = (int*)d_ws;                           // BATCH*MAXL ints = 512 KB

    lr_scan_kernel<<<BATCH, SEQ, 0, stream>>>(durations, max_len_p, ws_idx, out_mask);
    lr_expand_kernel<<<(BATCH * MAXL) / 8, 256, 0, stream>>>(
        (const float4*)x, ws_idx, (float4*)out);
}